// Round 9
// baseline (615.042 us; speedup 1.0000x reference)
//
#include <hip/hip_runtime.h>

// ============================================================================
// SimplePose head — round 19: restore r16 deconv1 (best total); deconv3
// MT 96->64 (pad waste 11%->5%, 3->4 blocks/CU, 1280->1792 blocks).
//
// r18 post-mortem: dbuf loosened wave timing -> per-XCD working set (7.3 MB
// = 4.2 w + 3.1 x) thrashes the 4 MB L2 -> FETCH 91->125, WRITE 140->173,
// dur 184->220.  The r16 lock-step 2-barrier schedule is TRAFFIC-OPTIMAL
// for this footprint; deconv1 frozen at the r16 body (193 us, total 536).
//
// r19 change (deconv3 only): MT 96->64.  425 pixels pad to 448 not 480
// (-6% MFMA), grid (7,4,64)=1792 blocks, LDS max(4*AN=34.6KB, y_s 33.8KB)
// = 34.6 KB -> 4 blocks/CU (launch_bounds (256,4); VGPR fits: acc shrinks
// MF 6->4).  NSUB=2 integer ✓; NITEM=1728 non-multiple-of-256 handled by
// existing guards.  Staging-row proof re-done for MT=64: consumed local
// row <= 5 < RSPAN=6 for all 7 tiles.
//
// Established: inputs f32, OUTPUT f32, pads-passthrough geometry:
//   x[64,8,6,2048] -> y1[64,14,10,256] -> y2[64,26,18,256]
//   -> (deconv3 + fused 1x1 head) hm[64,50,34,17] -> out[64,17,3].
// Parity (p,q), oh=2r+p: kh=(1-p)+2a, ih=r+a, tap t=a*2+b.
// bf16x3 split: x*w ~= xh*Wh + xh*Wl + xl*Wh (f32 MFMA acc).
// mfma_f32_16x16x32_bf16: A[m=lane&15][k=quad*8+j], B[k][n=lane&15],
//   D col=lane&15, row=quad*4+reg.
// deconv1 XCD pinning: ks = blockIdx.x%8 == XCD; lock-step 2-barrier
// schedule keeps the 7.3 MB/XCD working set L2-warm (r16-proven).
// Clamped staging rows (ih/ng) are proven never consumed for every tile.
// acc[]/rv[]/goff[] keep static indices everywhere (r6/r9 scratch bug).
// ============================================================================

#define BN_EPS 1e-5f

typedef __attribute__((ext_vector_type(8))) short short8;
typedef __attribute__((ext_vector_type(4))) short short4v;
typedef __attribute__((ext_vector_type(4))) float float4v;
typedef unsigned int uint;

__device__ __forceinline__ float4v mfma16(short8 a, short8 b, float4v c) {
  return __builtin_amdgcn_mfma_f32_16x16x32_bf16(a, b, c, 0, 0, 0);
}

// RNE f32 -> bf16 hi + bf16(residual) split
__device__ __forceinline__ void bf16split(float v, short& h, short& l) {
  const uint u  = __float_as_uint(v);
  const uint hb = (u + 0x7FFFu + ((u >> 16) & 1u)) >> 16;
  const float hf = __uint_as_float(hb << 16);
  const float lo = v - hf;
  const uint ul = __float_as_uint(lo);
  const uint lb = (ul + 0x7FFFu + ((ul >> 16) & 1u)) >> 16;
  h = (short)hb; l = (short)lb;
}

__device__ __forceinline__ uint pack2(short h0, short h1) {
  return (uint)(unsigned short)h0 | ((uint)(unsigned short)h1 << 16);
}

// ---------------------------------------------------------------------------
// Weight convert: [16 taps][CIN][256] f32 -> fragment order
//   frag id = (tap*NCH + ci_chunk)*16 + co_blk ; frag = [64 lanes][8 shorts]
//   lane = quad*16 + (co&15), element j: ci = ch*32 + quad*8 + j.
// grid (16, CIN/32, 8), 256 thr.
// ---------------------------------------------------------------------------
template <int CIN>
__global__ __launch_bounds__(256) void convert_w(
    const float* __restrict__ wg, short* __restrict__ wh, short* __restrict__ wl)
{
  constexpr int NCH = CIN / 32;
  __shared__ float tile[32][33];
  const int tap = blockIdx.x, ch = blockIdx.y, cb2 = blockIdx.z;  // 32-co block
  const int tid = threadIdx.x;
#pragma unroll
  for (int k = 0; k < 4; ++k) {
    const int idx = k * 256 + tid;
    const int ci_l = idx >> 5, co_l = idx & 31;
    tile[ci_l][co_l] =
        wg[((size_t)(tap * CIN) + ch * 32 + ci_l) * 256 + cb2 * 32 + co_l];
  }
  __syncthreads();
#pragma unroll
  for (int k = 0; k < 2; ++k) {
    const int dd = k * 256 + tid;        // dword id within 2 fragments
    const int f = dd >> 8, wd = dd & 255;
    const int lane = wd >> 2, jp = (wd & 3) * 2;
    const int quad = lane >> 4, lrow = lane & 15;
    const int ci_l = quad * 8 + jp, co_l = f * 16 + lrow;
    short h0, l0, h1, l1;
    bf16split(tile[ci_l][co_l], h0, l0);
    bf16split(tile[ci_l + 1][co_l], h1, l1);
    const size_t off = ((size_t)((tap * NCH + ch) * 16 + cb2 * 2 + f)) * 512 +
                       lane * 8 + jp;
    *(uint*)(wh + off) = pack2(h0, h1);
    *(uint*)(wl + off) = pack2(l0, l1);
  }
}

// wf [256,17] f32 -> head fragments (ch 0..7, co_blk 0..1).  grid(16) x 256.
__global__ __launch_bounds__(256) void convert_wf(
    const float* __restrict__ wf, short* __restrict__ wh, short* __restrict__ wl)
{
  const int b = blockIdx.x;                    // = ch*2 + co_blk
  const int ch = b >> 1, cb = b & 1;
  const int t = threadIdx.x;
  const int lane = t >> 2, jp = (t & 3) * 2;
  const int quad = lane >> 4, lrow = lane & 15;
  const int ci = ch * 32 + quad * 8 + jp;
  const int co = cb * 16 + lrow;
  const float v0 = (co < 17) ? wf[ci * 17 + co] : 0.f;
  const float v1 = (co < 17) ? wf[(ci + 1) * 17 + co] : 0.f;
  short h0, l0, h1, l1;
  bf16split(v0, h0, l0); bf16split(v1, h1, l1);
  const size_t off = (size_t)b * 512 + lane * 8 + jp;
  *(uint*)(wh + off) = pack2(h0, h1);
  *(uint*)(wl + off) = pack2(l0, l1);
}

// ---------------------------------------------------------------------------
// deconv2/3: block = (M-tile, parity, batch); 4 waves share M-tile, wave w
// owns co [w*64, w*64+64).  Input is PRE-SPLIT bf16 (yh/yl); staging is a
// pure short4 copy, double-buffered with one barrier per ci-chunk.
// !FUSE: epilogue writes split bf16 output (oh_/ol_).
//  FUSE: epilogue stages y as split bf16 planes in LDS (ALIASED onto the
//  dead staging buffers), runs 1x1 MFMA head.
// ---------------------------------------------------------------------------
template <int CIN, int H_IN, int W_IN, int MT, bool FUSE>
__global__ __launch_bounds__(256, 4) void deconv_mfma(
    const short* __restrict__ yh, const short* __restrict__ yl,
    const short* __restrict__ wbh, const short* __restrict__ wbl,
    const float* __restrict__ gg, const float* __restrict__ bg,
    const float* __restrict__ mg, const float* __restrict__ vg,
    float* __restrict__ og,                       // FUSE: heatmap out
    short* __restrict__ oh_, short* __restrict__ ol_,  // !FUSE: split out
    const short* __restrict__ wfh, const short* __restrict__ wfl,
    const float* __restrict__ bfg)
{
  constexpr int R = H_IN - 1, C = W_IN - 1, NPIX = R * C;
  constexpr int H_OUT = 2 * H_IN - 2, W_OUT = 2 * W_IN - 2;
  constexpr int MF = MT / 16;
  constexpr int NCH = CIN / 32;
  constexpr int OUTSPAN = (MT + C - 2) / C + 1;
  constexpr int RSPAN = OUTSPAN + 1;
  constexpr int CIP = 40;                  // 80 B row: 16B-aligned, bank-balanced
  constexpr int POS = RSPAN * W_IN;
  constexpr int AN = POS * CIP;
  constexpr int NITEM = POS * 16;          // short4 items/chunk (h + l halves)
  constexpr int NIT = (NITEM + 255) / 256;
  constexpr int YSP = 264;                 // y_s row stride (shorts): 16B-aligned

  // ---- unified LDS: staging (4*AN) and FUSE y_s planes (64*YSP) are
  // live in DISJOINT phases -> union them.
  constexpr int YS_SH = FUSE ? 64 * YSP : 1;
  constexpr int SMEM_SH = (4 * AN > YS_SH) ? 4 * AN : YS_SH;
  __shared__ __align__(16) short smem[SMEM_SH];
  short* const ah0 = smem;
  short* const ah1 = smem + AN;
  short* const al0 = smem + 2 * AN;
  short* const al1 = smem + 3 * AN;
  short* const ysh_s = smem;                    // FUSE epilogue alias
  short* const ysl_s = smem + 32 * YSP;

  const int tid = threadIdx.x;
  const int wid = tid >> 6, lane = tid & 63;
  const int quad = lane >> 4, lrow = lane & 15;
  const int n0 = wid << 6;
  const int p = (int)(blockIdx.y >> 1), q = (int)(blockIdx.y & 1);
  const int n = blockIdx.z;

  int tapid[4];
#pragma unroll
  for (int t = 0; t < 4; ++t)
    tapid[t] = ((1 - p + 2 * (t >> 1)) << 2) + (1 - q + 2 * (t & 1));

  const int p0 = (int)blockIdx.x * MT;
  const int r_base = p0 / C;

  int abase[MF];
#pragma unroll
  for (int mf = 0; mf < MF; ++mf) {
    int pidx = p0 + mf * 16 + lrow;
    if (pidx > NPIX - 1) pidx = NPIX - 1;
    const int r = pidx / C, c = pidx % C;
    abase[mf] = ((r - r_base) * W_IN + c) * CIP + (quad << 3);
  }

  // ---- staging item decode: item i = k*256+tid; pos=i>>4, half=(i>>3)&1,
  // sub=i&7.  half is a per-thread constant (256 % 16 == 0). ----
  const int s_half = (tid >> 3) & 1;             // 0: hi plane, 1: lo plane
  const short* __restrict__ gsrc = s_half ? yl : yh;
  int s_goff[NIT], s_loff[NIT];
#pragma unroll
  for (int k = 0; k < NIT; ++k) {
    const int i = k * 256 + tid;
    const int pos = i >> 4, sub = i & 7;
    const int row = pos / W_IN, col = pos - row * W_IN;
    int ih = r_base + row;
    if (ih > H_IN - 1) ih = H_IN - 1;            // clamp: rows >= H_IN unread
    s_goff[k] = ((n * H_IN + ih) * W_IN + col) * CIN + sub * 4;
    s_loff[k] = pos * CIP + sub * 4;
  }

  float4v acc[MF][4];
#pragma unroll
  for (int mf = 0; mf < MF; ++mf)
#pragma unroll
    for (int nf = 0; nf < 4; ++nf) acc[mf][nf] = (float4v){0.f, 0.f, 0.f, 0.f};

  short4v rv[NIT];
  // ---- prologue: stage chunk 0 into buf 0 ----
#pragma unroll
  for (int k = 0; k < NIT; ++k)
    if (NITEM % 256 == 0 || k * 256 + tid < NITEM)
      rv[k] = *(const short4v*)(gsrc + s_goff[k]);
  {
    short* lb = s_half ? al0 : ah0;
#pragma unroll
    for (int k = 0; k < NIT; ++k)
      if (NITEM % 256 == 0 || k * 256 + tid < NITEM)
        *(short4v*)(lb + s_loff[k]) = rv[k];
  }
  __syncthreads();

  // ---- main loop: one barrier per chunk; loads issued before compute ----
#pragma unroll 1
  for (int ck = 0; ck < NCH; ++ck) {
    const int b = ck & 1;
    const bool pre = (ck + 1 < NCH);
    if (pre) {
      const int ci0 = (ck + 1) * 32;
#pragma unroll
      for (int k = 0; k < NIT; ++k)
        if (NITEM % 256 == 0 || k * 256 + tid < NITEM)
          rv[k] = *(const short4v*)(gsrc + s_goff[k] + ci0);
    }
    const short* ab  = b ? ah1 : ah0;
    const short* alp = b ? al1 : al0;
#pragma unroll
    for (int t = 0; t < 4; ++t) {
      short8 Bh[4], Bl[4];
#pragma unroll
      for (int nf = 0; nf < 4; ++nf) {
        const size_t fo =
            ((size_t)((tapid[t] * NCH + ck) * 16 + (wid << 2) + nf)) * 512 + lane * 8;
        Bh[nf] = *(const short8*)(wbh + fo);
        Bl[nf] = *(const short8*)(wbl + fo);
      }
      const int toff = ((t >> 1) * W_IN + (t & 1)) * CIP;
#pragma unroll
      for (int mf = 0; mf < MF; ++mf) {
        const short8 Ah = *(const short8*)(ab + abase[mf] + toff);
        const short8 Al = *(const short8*)(alp + abase[mf] + toff);
#pragma unroll
        for (int nf = 0; nf < 4; ++nf) {
          acc[mf][nf] = mfma16(Ah, Bh[nf], acc[mf][nf]);
          acc[mf][nf] = mfma16(Ah, Bl[nf], acc[mf][nf]);
          acc[mf][nf] = mfma16(Al, Bh[nf], acc[mf][nf]);
        }
      }
    }
    if (pre) {
      short* lb = s_half ? (b ? al0 : al1) : (b ? ah0 : ah1);
#pragma unroll
      for (int k = 0; k < NIT; ++k)
        if (NITEM % 256 == 0 || k * 256 + tid < NITEM)
          *(short4v*)(lb + s_loff[k]) = rv[k];
    }
    __syncthreads();
  }

  float scv[4], shv[4];
#pragma unroll
  for (int nf = 0; nf < 4; ++nf) {
    const int co = n0 + nf * 16 + lrow;
    const float sc = gg[co] * rsqrtf(vg[co] + BN_EPS);
    scv[nf] = sc; shv[nf] = bg[co] - mg[co] * sc;
  }

  if constexpr (!FUSE) {
#pragma unroll
    for (int mf = 0; mf < MF; ++mf)
#pragma unroll
      for (int reg = 0; reg < 4; ++reg) {
        const int pidx = p0 + mf * 16 + (quad << 2) + reg;
        if (pidx < NPIX) {
          const int r = pidx / C, c = pidx % C;
          const int oh = 2 * r + p, ow = 2 * c + q;
          const size_t base =
              ((size_t)(n * H_OUT + oh) * W_OUT + ow) * 256 + n0 + lrow;
#pragma unroll
          for (int nf = 0; nf < 4; ++nf) {
            const float v = fmaxf(0.f, fmaf(acc[mf][nf][reg], scv[nf], shv[nf]));
            short h, l; bf16split(v, h, l);
            oh_[base + nf * 16] = h;
            ol_[base + nf * 16] = l;
          }
        }
      }
  } else {
    constexpr int NSUB = MT / 32;
    const int co_out = (wid << 4) + lrow;       // head channel (waves 0,1)
#pragma unroll                                  // FULL unroll: static acc idx
    for (int s = 0; s < NSUB; ++s) {
      __syncthreads();
#pragma unroll
      for (int mh = 0; mh < 2; ++mh) {
        const int mf = 2 * s + mh;
        const int pl = (mh << 4) + (quad << 2);
#pragma unroll
        for (int reg = 0; reg < 4; ++reg)
#pragma unroll
          for (int nf = 0; nf < 4; ++nf) {
            const float v = fmaxf(0.f, fmaf(acc[mf][nf][reg], scv[nf], shv[nf]));
            short h, l; bf16split(v, h, l);
            const int o = (pl + reg) * YSP + n0 + nf * 16 + lrow;
            ysh_s[o] = h; ysl_s[o] = l;
          }
      }
      __syncthreads();
      if (wid < 2) {
        float4v hacc[2];
        hacc[0] = (float4v){0.f, 0.f, 0.f, 0.f};
        hacc[1] = (float4v){0.f, 0.f, 0.f, 0.f};
#pragma unroll
        for (int ch = 0; ch < 8; ++ch) {
          const size_t bo = (size_t)(ch * 2 + wid) * 512 + lane * 8;
          const short8 Hh = *(const short8*)(wfh + bo);
          const short8 Hl = *(const short8*)(wfl + bo);
#pragma unroll
          for (int mh = 0; mh < 2; ++mh) {
            const int yo = (mh * 16 + lrow) * YSP + (ch << 5) + (quad << 3);
            const short8 Ah = *(const short8*)(ysh_s + yo);
            const short8 Al = *(const short8*)(ysl_s + yo);
            hacc[mh] = mfma16(Ah, Hh, hacc[mh]);
            hacc[mh] = mfma16(Ah, Hl, hacc[mh]);
            hacc[mh] = mfma16(Al, Hh, hacc[mh]);
          }
        }
        if (co_out < 17) {
          const float bias = bfg[co_out];
#pragma unroll
          for (int mh = 0; mh < 2; ++mh)
#pragma unroll
            for (int reg = 0; reg < 4; ++reg) {
              const int pidx = p0 + s * 32 + mh * 16 + (quad << 2) + reg;
              if (pidx < NPIX) {
                const int r = pidx / C, c = pidx % C;
                const int oh = 2 * r + p, ow = 2 * c + q;
                og[((size_t)(n * H_OUT + oh) * W_OUT + ow) * 17 + co_out] =
                    hacc[mh][reg] + bias;
              }
            }
        }
      }
    }
  }
}

// ---------------------------------------------------------------------------
// deconv1: batch folded into M (2240), MT=112 -> 20 tiles; K-split x8 over
// ci; partial accumulation into P0 (ks 0-3) / P1 (ks 4-7); reduction + BN
// in bn1_reduce_split.  EXACT r16 body (best-total-proven 536 us config):
// 256 thr / 4 waves, single-buffer LDS 30.7 KB, lock-step 2-barrier chunk
// schedule (keeps 7.3 MB/XCD working set L2-warm), issue-early loads.
// 1D grid(640): ks = id%8 (== XCD), slot=id/8, tile=slot%20, py=slot/20.
// ---------------------------------------------------------------------------
template <int MT, int KS>
__global__ __launch_bounds__(256, 2) void deconv1_mfma(
    const float* __restrict__ xg,
    const short* __restrict__ wbh, const short* __restrict__ wbl,
    float* __restrict__ P0, float* __restrict__ P1)
{
  constexpr int CIN = 2048, NCH = 64, H_IN = 8, W_IN = 6;
  constexpr int MF = MT / 16;              // 7
  constexpr int NSPAN = 4, CIP = 40;
  constexpr int NCK = CIN / 32 / KS;       // 8 ci-chunks per block
  constexpr int NTILE = 2240 / MT;         // 20
  constexpr int POS = NSPAN * 48;          // 192 staged positions
  constexpr int AN = POS * CIP;            // 7680 shorts per plane
  constexpr int NIT = POS * 16 / 256;      // 12 float2 items per thread

  __shared__ __align__(16) short ah_s[AN];
  __shared__ __align__(16) short al_s[AN];

  const int tid = threadIdx.x;
  const int wid = tid >> 6, lane = tid & 63;
  const int quad = lane >> 4, lrow = lane & 15;
  const int n0 = wid << 6;

  // ---- XCD-aware work decode (r14/r16-proven) ----
  const int id = (int)blockIdx.x;
  const int ks = id & 7;                   // K-split slice == XCD
  const int slot = id >> 3;                // 0..79
  const int tile = slot % NTILE;
  const int py = slot / NTILE;             // parity index 0..3
  const int p = py >> 1, q = py & 1;

  int tapid[4];
#pragma unroll
  for (int t = 0; t < 4; ++t)
    tapid[t] = ((1 - p + 2 * (t >> 1)) << 2) + (1 - q + 2 * (t & 1));

  const int m0 = tile * MT;
  const int n_base = m0 / 35;

  int abase[MF];
#pragma unroll
  for (int mf = 0; mf < MF; ++mf) {
    const int mg_ = m0 + mf * 16 + lrow;   // < 2240 always
    const int nl = mg_ / 35 - n_base;      // <= 3 (m0%35 in {0,7,14,21,28})
    const int pix = mg_ % 35;
    const int r = pix / 5, c = pix % 5;
    abase[mf] = ((nl * H_IN + r) * W_IN + c) * CIP + (quad << 3);
  }

  // ---- staging offsets: item i = k*256+tid; cc2 = tid&15 (const!),
  // pos = k*16 + (tid>>4). ----
  const int tp = tid >> 4, cc2 = tid & 15;
  int goff[NIT];
#pragma unroll
  for (int k = 0; k < NIT; ++k) {
    const int pos = k * 16 + tp;
    const int nl = pos / 48, loc = pos - nl * 48;
    int ng = n_base + nl;
    if (ng > 63) ng = 63;                  // clamp: never consumed
    goff[k] = (ng * 48 + loc) * CIN + cc2 * 2;
  }
  const int loff0 = tp * CIP + cc2 * 2;

  float4v acc[MF][4];
#pragma unroll
  for (int mf = 0; mf < MF; ++mf)
#pragma unroll
    for (int nf = 0; nf < 4; ++nf) acc[mf][nf] = (float4v){0.f, 0.f, 0.f, 0.f};

  const int cibase = ks * (CIN / KS);
  float2 rv[NIT];
  // ---- prologue: load chunk 0 ----
#pragma unroll
  for (int k = 0; k < NIT; ++k)
    rv[k] = *(const float2*)(xg + goff[k] + cibase);

  // ---- main loop: single buffer; sync -> write regs -> sync -> issue next
  // loads -> compute (r16 lock-step; traffic-optimal for 7.3 MB/XCD). ----
#pragma unroll 1
  for (int ck = 0; ck < NCK; ++ck) {
    __syncthreads();                       // prior compute done reading buf
#pragma unroll
    for (int k = 0; k < NIT; ++k) {
      short h0, l0, h1, l1;
      bf16split(rv[k].x, h0, l0); bf16split(rv[k].y, h1, l1);
      const int o = loff0 + k * 16 * CIP;
      *(uint*)(ah_s + o) = pack2(h0, h1);
      *(uint*)(al_s + o) = pack2(l0, l1);
    }
    __syncthreads();                       // buf ready
    if (ck + 1 < NCK) {
      const int ci0 = cibase + (ck + 1) * 32;
#pragma unroll
      for (int k = 0; k < NIT; ++k)
        rv[k] = *(const float2*)(xg + goff[k] + ci0);
    }
    const int ch = ks * NCK + ck;          // global ci-chunk id for weights
#pragma unroll
    for (int t = 0; t < 4; ++t) {
      short8 Bh[4], Bl[4];
#pragma unroll
      for (int nf = 0; nf < 4; ++nf) {
        const size_t fo =
            ((size_t)((tapid[t] * NCH + ch) * 16 + (wid << 2) + nf)) * 512 + lane * 8;
        Bh[nf] = *(const short8*)(wbh + fo);
        Bl[nf] = *(const short8*)(wbl + fo);
      }
      const int toff = ((t >> 1) * W_IN + (t & 1)) * CIP;
#pragma unroll
      for (int mf = 0; mf < MF; ++mf) {
        const short8 Ah = *(const short8*)(ah_s + abase[mf] + toff);
        const short8 Al = *(const short8*)(al_s + abase[mf] + toff);
#pragma unroll
        for (int nf = 0; nf < 4; ++nf) {
          acc[mf][nf] = mfma16(Ah, Bh[nf], acc[mf][nf]);
          acc[mf][nf] = mfma16(Ah, Bl[nf], acc[mf][nf]);
          acc[mf][nf] = mfma16(Al, Bh[nf], acc[mf][nf]);
        }
      }
    }
  }

  // partial accumulation: ks 0-3 -> P0, ks 4-7 -> P1 (4-way contention each)
  float* __restrict__ Pb = (ks & 4) ? P1 : P0;
#pragma unroll
  for (int mf = 0; mf < MF; ++mf)
#pragma unroll
    for (int reg = 0; reg < 4; ++reg) {
      const int mg_ = m0 + mf * 16 + (quad << 2) + reg;
      const int nn = mg_ / 35, pix = mg_ % 35;
      const int r = pix / 5, c = pix % 5;
      const int oh = 2 * r + p, ow = 2 * c + q;
      float* dst = Pb + ((size_t)(nn * 14 + oh) * 10 + ow) * 256 + n0 + lrow;
#pragma unroll
      for (int nf = 0; nf < 4; ++nf)
        atomicAdd(dst + nf * 16, acc[mf][nf][reg]);
    }
}

// P0+P1 -> BN -> ReLU -> split bf16 planes y1h/y1l (co = elem & 255).
__global__ __launch_bounds__(256) void bn1_reduce_split(
    const float* __restrict__ P0, const float* __restrict__ P1,
    short* __restrict__ yh, short* __restrict__ yl,
    const float* __restrict__ gg, const float* __restrict__ bg,
    const float* __restrict__ mg, const float* __restrict__ vg, int nquad)
{
  for (int i = blockIdx.x * 256 + threadIdx.x; i < nquad; i += gridDim.x * 256) {
    const float4v a = *(const float4v*)(P0 + (size_t)i * 4);
    const float4v b = *(const float4v*)(P1 + (size_t)i * 4);
    const int co0 = (i * 4) & 255;
    short4v hv, lv;
#pragma unroll
    for (int j = 0; j < 4; ++j) {
      const int co = co0 + j;
      const float sc = gg[co] * rsqrtf(vg[co] + BN_EPS);
      const float v = fmaxf(0.f, fmaf(a[j] + b[j], sc, bg[co] - mg[co] * sc));
      short h, l; bf16split(v, h, l);
      hv[j] = h; lv[j] = l;
    }
    *(short4v*)(yh + (size_t)i * 4) = hv;
    *(short4v*)(yl + (size_t)i * 4) = lv;
  }
}

// ---------------------------------------------------------------------------
// Heatmap max detection on [64, 50, 34, 17]: one block per (b, k).
// ---------------------------------------------------------------------------
__global__ __launch_bounds__(256) void heatmap_det(const float* __restrict__ hm,
                                                   float* __restrict__ out)
{
  constexpr int H = 50, W = 34, HW = H * W, K = 17;
  const int b = blockIdx.x, k = blockIdx.y;
  const int tid = threadIdx.x;

  float best = -INFINITY;
  int bi = 0;
  for (int pos = tid; pos < HW; pos += 256) {
    const float v = hm[((size_t)b * HW + pos) * K + k];
    if (v > best) { best = v; bi = pos; }
  }
  __shared__ float sv[256];
  __shared__ int si[256];
  sv[tid] = best; si[tid] = bi;
  __syncthreads();
  for (int s = 128; s > 0; s >>= 1) {
    if (tid < s) {
      const float v2 = sv[tid + s]; const int i2 = si[tid + s];
      if (v2 > sv[tid] || (v2 == sv[tid] && i2 < si[tid])) { sv[tid] = v2; si[tid] = i2; }
    }
    __syncthreads();
  }
  if (tid == 0) {
    const float score = sv[0];
    const int idx = si[0];
    float ptx = 0.f, pty = 0.f;
    if (score > 0.f) {
      const int px = idx % W, py = idx / W;
      float dx = 0.f, dy = 0.f;
      if (px > 0 && px < W - 1 && py > 0 && py < H - 1) {
        auto g = [&](int off) {
          int i = idx + off;
          i = i < 0 ? 0 : (i > HW - 1 ? HW - 1 : i);
          return hm[((size_t)b * HW + i) * K + k];
        };
        const float d1 = g(1) - g(-1);
        const float d2 = g(W) - g(-W);
        dx = d1 > 0.f ? 0.25f : (d1 < 0.f ? -0.25f : 0.f);
        dy = d2 > 0.f ? 0.25f : (d2 < 0.f ? -0.25f : 0.f);
      }
      ptx = (float)px + dx;
      pty = (float)py + dy;
    }
    out[((size_t)b * K + k) * 3 + 0] = ptx;
    out[((size_t)b * K + k) * 3 + 1] = pty;
    out[((size_t)b * K + k) * 3 + 2] = score;
  }
}

// ---------------------------------------------------------------------------
extern "C" void kernel_launch(void* const* d_in, const int* in_sizes, int n_in,
                              void* d_out, int out_size, void* d_ws, size_t ws_size,
                              hipStream_t stream)
{
  const float* x  = (const float*)d_in[0];
  const float* w1 = (const float*)d_in[1];
  const float* g1 = (const float*)d_in[2];
  const float* b1 = (const float*)d_in[3];
  const float* m1 = (const float*)d_in[4];
  const float* v1 = (const float*)d_in[5];
  const float* w2 = (const float*)d_in[6];
  const float* g2 = (const float*)d_in[7];
  const float* b2 = (const float*)d_in[8];
  const float* m2 = (const float*)d_in[9];
  const float* v2 = (const float*)d_in[10];
  const float* w3 = (const float*)d_in[11];
  const float* g3 = (const float*)d_in[12];
  const float* b3 = (const float*)d_in[13];
  const float* m3 = (const float*)d_in[14];
  const float* v3 = (const float*)d_in[15];
  const float* wf = (const float*)d_in[16];
  const float* bf = (const float*)d_in[17];

  char* ws = (char*)d_ws;
  // Timeline-aliased layout (max offset 51,904,512 -- same as r16):
  //   region                 live span                 bytes
  //   P0      [0, 9,175,040)           deconv1 -> bn1_reduce
  //   P1      [9,175,040, 18,350,080)  deconv1 -> bn1_reduce
  //   y2h     [0, 15,335,424)          deconv2 -> deconv3   (alias P, dead)
  //   hm      [15,335,424, 22,733,824) deconv3 -> det  (alias y2h-end+y1h)
  //   w1h/w1l [18,350,080, 51,904,512) convert -> deconv1
  //   y1h     [18,350,080, 22,937,600) bn1 -> deconv2  (alias dead w1)
  //   y1l     [22,937,600, 27,525,120) bn1 -> deconv2
  //   y2l     [27,525,120, 42,860,544) deconv2 -> deconv3 (dead w1 tail)
  //   w2h/w2l [42,860,544, 47,054,848) convert(after deconv1) -> deconv2
  //   w3h/w3l [47,054,848, 51,249,152) convert(after deconv1) -> deconv3
  //   wfh/wfl [51,249,152, 51,281,920) convert(after deconv1) -> deconv3
  float* P0  = (float*)(ws + 0);
  float* P1  = (float*)(ws + 9175040);
  short* y2h = (short*)(ws + 0);
  float* hm  = (float*)(ws + 15335424);
  short* w1h = (short*)(ws + 18350080);
  short* w1l = (short*)(ws + 35127296);
  short* y1h = (short*)(ws + 18350080);
  short* y1l = (short*)(ws + 22937600);
  short* y2l = (short*)(ws + 27525120);
  short* w2h = (short*)(ws + 42860544);
  short* w2l = (short*)(ws + 44957696);
  short* w3h = (short*)(ws + 47054848);
  short* w3l = (short*)(ws + 49152000);
  short* wfh = (short*)(ws + 51249152);
  short* wfl = (short*)(ws + 51265536);

  // w1 conversion + partial-buffer zero-init
  convert_w<2048><<<dim3(16, 64, 8), 256, 0, stream>>>(w1, w1h, w1l);
  hipMemsetAsync(P0, 0, 18350080, stream);      // covers P0 and P1

  // deconv1: K-split x8, partials into P0/P1, then reduce+BN+ReLU+split
  deconv1_mfma<112, 8><<<dim3(640), 256, 0, stream>>>(x, w1h, w1l, P0, P1);
  bn1_reduce_split<<<dim3(1024), 256, 0, stream>>>(P0, P1, y1h, y1l,
                                                   g1, b1, m1, v1,
                                                   64 * 14 * 10 * 256 / 4);

  // w2/w3/wf conversion into the now-dead w1 region
  convert_w<256><<<dim3(16, 8, 8), 256, 0, stream>>>(w2, w2h, w2l);
  convert_w<256><<<dim3(16, 8, 8), 256, 0, stream>>>(w3, w3h, w3l);
  convert_wf<<<dim3(16), 256, 0, stream>>>(wf, wfh, wfl);

  // deconv2: NPIX=117, MT=32 -> 4 tiles -> 1024 blocks; split bf16 out
  deconv_mfma<256, 14, 10, 32, false><<<dim3(4, 4, 64), 256, 0, stream>>>(
      y1h, y1l, w2h, w2l, g2, b2, m2, v2, nullptr, y2h, y2l,
      nullptr, nullptr, nullptr);

  // deconv3 + fused MFMA head: NPIX=425, MT=64 -> 7 tiles -> 1792 blocks
  // (pad 448/425 = 95% eff; LDS 34.6 KB -> 4 blocks/CU)
  deconv_mfma<256, 26, 18, 64, true><<<dim3(7, 4, 64), 256, 0, stream>>>(
      y2h, y2l, w3h, w3l, g3, b3, m3, v3, hm, nullptr, nullptr, wfh, wfl, bf);

  // detection
  heatmap_det<<<dim3(64, 17), 256, 0, stream>>>(hm, (float*)d_out);
}

// Round 10
// 520.821 us; speedup vs baseline: 1.1809x; 1.1809x over previous
//
#include <hip/hip_runtime.h>

// ============================================================================
// SimplePose head — round 20: revert r19's spill; XCD-pin deconv3.
//
// r19 post-mortem: changing the SHARED deconv_mfma launch_bounds (256,2)->
// (256,4) capped VGPR at 128 -> FUSE variant spilled acc to scratch
// (VGPR_Count 64, WRITE 211 MB vs 7.4 MB hm, FETCH 345 MB, 250 us at the
// 2.28 TB/s wall).  Revert launch_bounds to (256,2) and deconv3 MT to 96
// (r16 config, 536 us proven).
//
// r20 change (deconv3 launch mapping only): 1D grid(1280) with XCD pinning
// (r14-proven mechanism, no atomics in deconv3 so no r15 ping-pong risk):
//   xcd = id&7: py = xcd>>1 (one parity per XCD pair -> its 1 MB w3 slice
//   L2-resident), half = xcd&1; slot = id>>3: tile = slot%5, n = half*32 +
//   slot/5 (5 consecutive blocks share one batch's 479 KB y2 window).
//
// Established: inputs f32, OUTPUT f32, pads-passthrough geometry:
//   x[64,8,6,2048] -> y1[64,14,10,256] -> y2[64,26,18,256]
//   -> (deconv3 + fused 1x1 head) hm[64,50,34,17] -> out[64,17,3].
// Parity (p,q), oh=2r+p: kh=(1-p)+2a, ih=r+a, tap t=a*2+b.
// bf16x3 split: x*w ~= xh*Wh + xh*Wl + xl*Wh (f32 MFMA acc).
// mfma_f32_16x16x32_bf16: A[m=lane&15][k=quad*8+j], B[k][n=lane&15],
//   D col=lane&15, row=quad*4+reg.
// deconv1 XCD pinning: ks = blockIdx.x%8 == XCD; lock-step 2-barrier
// schedule keeps the 7.3 MB/XCD working set L2-warm (r16-proven).
// Clamped staging rows (ih/ng) are proven never consumed for every tile.
// acc[]/rv[]/goff[] keep static indices everywhere (r6/r9 scratch bug;
// r19 added: never tighten launch_bounds on a shared template).
// ============================================================================

#define BN_EPS 1e-5f

typedef __attribute__((ext_vector_type(8))) short short8;
typedef __attribute__((ext_vector_type(4))) short short4v;
typedef __attribute__((ext_vector_type(4))) float float4v;
typedef unsigned int uint;

__device__ __forceinline__ float4v mfma16(short8 a, short8 b, float4v c) {
  return __builtin_amdgcn_mfma_f32_16x16x32_bf16(a, b, c, 0, 0, 0);
}

// RNE f32 -> bf16 hi + bf16(residual) split
__device__ __forceinline__ void bf16split(float v, short& h, short& l) {
  const uint u  = __float_as_uint(v);
  const uint hb = (u + 0x7FFFu + ((u >> 16) & 1u)) >> 16;
  const float hf = __uint_as_float(hb << 16);
  const float lo = v - hf;
  const uint ul = __float_as_uint(lo);
  const uint lb = (ul + 0x7FFFu + ((ul >> 16) & 1u)) >> 16;
  h = (short)hb; l = (short)lb;
}

__device__ __forceinline__ uint pack2(short h0, short h1) {
  return (uint)(unsigned short)h0 | ((uint)(unsigned short)h1 << 16);
}

// ---------------------------------------------------------------------------
// Weight convert: [16 taps][CIN][256] f32 -> fragment order
//   frag id = (tap*NCH + ci_chunk)*16 + co_blk ; frag = [64 lanes][8 shorts]
//   lane = quad*16 + (co&15), element j: ci = ch*32 + quad*8 + j.
// grid (16, CIN/32, 8), 256 thr.
// ---------------------------------------------------------------------------
template <int CIN>
__global__ __launch_bounds__(256) void convert_w(
    const float* __restrict__ wg, short* __restrict__ wh, short* __restrict__ wl)
{
  constexpr int NCH = CIN / 32;
  __shared__ float tile[32][33];
  const int tap = blockIdx.x, ch = blockIdx.y, cb2 = blockIdx.z;  // 32-co block
  const int tid = threadIdx.x;
#pragma unroll
  for (int k = 0; k < 4; ++k) {
    const int idx = k * 256 + tid;
    const int ci_l = idx >> 5, co_l = idx & 31;
    tile[ci_l][co_l] =
        wg[((size_t)(tap * CIN) + ch * 32 + ci_l) * 256 + cb2 * 32 + co_l];
  }
  __syncthreads();
#pragma unroll
  for (int k = 0; k < 2; ++k) {
    const int dd = k * 256 + tid;        // dword id within 2 fragments
    const int f = dd >> 8, wd = dd & 255;
    const int lane = wd >> 2, jp = (wd & 3) * 2;
    const int quad = lane >> 4, lrow = lane & 15;
    const int ci_l = quad * 8 + jp, co_l = f * 16 + lrow;
    short h0, l0, h1, l1;
    bf16split(tile[ci_l][co_l], h0, l0);
    bf16split(tile[ci_l + 1][co_l], h1, l1);
    const size_t off = ((size_t)((tap * NCH + ch) * 16 + cb2 * 2 + f)) * 512 +
                       lane * 8 + jp;
    *(uint*)(wh + off) = pack2(h0, h1);
    *(uint*)(wl + off) = pack2(l0, l1);
  }
}

// wf [256,17] f32 -> head fragments (ch 0..7, co_blk 0..1).  grid(16) x 256.
__global__ __launch_bounds__(256) void convert_wf(
    const float* __restrict__ wf, short* __restrict__ wh, short* __restrict__ wl)
{
  const int b = blockIdx.x;                    // = ch*2 + co_blk
  const int ch = b >> 1, cb = b & 1;
  const int t = threadIdx.x;
  const int lane = t >> 2, jp = (t & 3) * 2;
  const int quad = lane >> 4, lrow = lane & 15;
  const int ci = ch * 32 + quad * 8 + jp;
  const int co = cb * 16 + lrow;
  const float v0 = (co < 17) ? wf[ci * 17 + co] : 0.f;
  const float v1 = (co < 17) ? wf[(ci + 1) * 17 + co] : 0.f;
  short h0, l0, h1, l1;
  bf16split(v0, h0, l0); bf16split(v1, h1, l1);
  const size_t off = (size_t)b * 512 + lane * 8 + jp;
  *(uint*)(wh + off) = pack2(h0, h1);
  *(uint*)(wl + off) = pack2(l0, l1);
}

// ---------------------------------------------------------------------------
// deconv2/3: 4 waves share M-tile, wave w owns co [w*64, w*64+64).  Input is
// PRE-SPLIT bf16 (yh/yl); staging is a pure short4 copy, double-buffered
// with one barrier per ci-chunk.
// XCDMAP=false: grid (tiles, 4, 64) 3D decode (deconv2).
// XCDMAP=true : grid 1D; xcd=id&7 -> py=xcd>>1, half=xcd&1; slot=id>>3 ->
//               tile=slot%NTILE, n=half*32+slot/NTILE (deconv3: per-XCD
//               w3 parity slice 1 MB L2-resident, y2 batch-windowed).
// !FUSE: epilogue writes split bf16 output (oh_/ol_).
//  FUSE: epilogue stages y as split bf16 planes in LDS (ALIASED onto the
//  dead staging buffers), runs 1x1 MFMA head.
// ---------------------------------------------------------------------------
template <int CIN, int H_IN, int W_IN, int MT, bool FUSE, bool XCDMAP>
__global__ __launch_bounds__(256, 2) void deconv_mfma(
    const short* __restrict__ yh, const short* __restrict__ yl,
    const short* __restrict__ wbh, const short* __restrict__ wbl,
    const float* __restrict__ gg, const float* __restrict__ bg,
    const float* __restrict__ mg, const float* __restrict__ vg,
    float* __restrict__ og,                       // FUSE: heatmap out
    short* __restrict__ oh_, short* __restrict__ ol_,  // !FUSE: split out
    const short* __restrict__ wfh, const short* __restrict__ wfl,
    const float* __restrict__ bfg)
{
  constexpr int R = H_IN - 1, C = W_IN - 1, NPIX = R * C;
  constexpr int H_OUT = 2 * H_IN - 2, W_OUT = 2 * W_IN - 2;
  constexpr int MF = MT / 16;
  constexpr int NCH = CIN / 32;
  constexpr int NTILE = (NPIX + MT - 1) / MT;
  constexpr int OUTSPAN = (MT + C - 2) / C + 1;
  constexpr int RSPAN = OUTSPAN + 1;
  constexpr int CIP = 40;                  // 80 B row: 16B-aligned, bank-balanced
  constexpr int POS = RSPAN * W_IN;
  constexpr int AN = POS * CIP;
  constexpr int NITEM = POS * 16;          // short4 items/chunk (h + l halves)
  constexpr int NIT = (NITEM + 255) / 256;
  constexpr int YSP = 264;                 // y_s row stride (shorts): 16B-aligned

  // ---- unified LDS: staging (4*AN) and FUSE y_s planes (64*YSP) are
  // live in DISJOINT phases -> union them.
  constexpr int YS_SH = FUSE ? 64 * YSP : 1;
  constexpr int SMEM_SH = (4 * AN > YS_SH) ? 4 * AN : YS_SH;
  __shared__ __align__(16) short smem[SMEM_SH];
  short* const ah0 = smem;
  short* const ah1 = smem + AN;
  short* const al0 = smem + 2 * AN;
  short* const al1 = smem + 3 * AN;
  short* const ysh_s = smem;                    // FUSE epilogue alias
  short* const ysl_s = smem + 32 * YSP;

  const int tid = threadIdx.x;
  const int wid = tid >> 6, lane = tid & 63;
  const int quad = lane >> 4, lrow = lane & 15;
  const int n0 = wid << 6;

  int p, q, n, p0;
  if constexpr (XCDMAP) {
    const int id = (int)blockIdx.x;
    const int xcd = id & 7, slot = id >> 3;      // slot 0..(NTILE*32-1)
    const int py = xcd >> 1, half = xcd & 1;
    p = py >> 1; q = py & 1;
    p0 = (slot % NTILE) * MT;
    n = half * 32 + slot / NTILE;
  } else {
    p = (int)(blockIdx.y >> 1); q = (int)(blockIdx.y & 1);
    n = (int)blockIdx.z;
    p0 = (int)blockIdx.x * MT;
  }

  int tapid[4];
#pragma unroll
  for (int t = 0; t < 4; ++t)
    tapid[t] = ((1 - p + 2 * (t >> 1)) << 2) + (1 - q + 2 * (t & 1));

  const int r_base = p0 / C;

  int abase[MF];
#pragma unroll
  for (int mf = 0; mf < MF; ++mf) {
    int pidx = p0 + mf * 16 + lrow;
    if (pidx > NPIX - 1) pidx = NPIX - 1;
    const int r = pidx / C, c = pidx % C;
    abase[mf] = ((r - r_base) * W_IN + c) * CIP + (quad << 3);
  }

  // ---- staging item decode: item i = k*256+tid; pos=i>>4, half=(i>>3)&1,
  // sub=i&7.  half is a per-thread constant (256 % 16 == 0). ----
  const int s_half = (tid >> 3) & 1;             // 0: hi plane, 1: lo plane
  const short* __restrict__ gsrc = s_half ? yl : yh;
  int s_goff[NIT], s_loff[NIT];
#pragma unroll
  for (int k = 0; k < NIT; ++k) {
    const int i = k * 256 + tid;
    const int pos = i >> 4, sub = i & 7;
    const int row = pos / W_IN, col = pos - row * W_IN;
    int ih = r_base + row;
    if (ih > H_IN - 1) ih = H_IN - 1;            // clamp: rows >= H_IN unread
    s_goff[k] = ((n * H_IN + ih) * W_IN + col) * CIN + sub * 4;
    s_loff[k] = pos * CIP + sub * 4;
  }

  float4v acc[MF][4];
#pragma unroll
  for (int mf = 0; mf < MF; ++mf)
#pragma unroll
    for (int nf = 0; nf < 4; ++nf) acc[mf][nf] = (float4v){0.f, 0.f, 0.f, 0.f};

  short4v rv[NIT];
  // ---- prologue: stage chunk 0 into buf 0 ----
#pragma unroll
  for (int k = 0; k < NIT; ++k)
    if (NITEM % 256 == 0 || k * 256 + tid < NITEM)
      rv[k] = *(const short4v*)(gsrc + s_goff[k]);
  {
    short* lb = s_half ? al0 : ah0;
#pragma unroll
    for (int k = 0; k < NIT; ++k)
      if (NITEM % 256 == 0 || k * 256 + tid < NITEM)
        *(short4v*)(lb + s_loff[k]) = rv[k];
  }
  __syncthreads();

  // ---- main loop: one barrier per chunk; loads issued before compute ----
#pragma unroll 1
  for (int ck = 0; ck < NCH; ++ck) {
    const int b = ck & 1;
    const bool pre = (ck + 1 < NCH);
    if (pre) {
      const int ci0 = (ck + 1) * 32;
#pragma unroll
      for (int k = 0; k < NIT; ++k)
        if (NITEM % 256 == 0 || k * 256 + tid < NITEM)
          rv[k] = *(const short4v*)(gsrc + s_goff[k] + ci0);
    }
    const short* ab  = b ? ah1 : ah0;
    const short* alp = b ? al1 : al0;
#pragma unroll
    for (int t = 0; t < 4; ++t) {
      short8 Bh[4], Bl[4];
#pragma unroll
      for (int nf = 0; nf < 4; ++nf) {
        const size_t fo =
            ((size_t)((tapid[t] * NCH + ck) * 16 + (wid << 2) + nf)) * 512 + lane * 8;
        Bh[nf] = *(const short8*)(wbh + fo);
        Bl[nf] = *(const short8*)(wbl + fo);
      }
      const int toff = ((t >> 1) * W_IN + (t & 1)) * CIP;
#pragma unroll
      for (int mf = 0; mf < MF; ++mf) {
        const short8 Ah = *(const short8*)(ab + abase[mf] + toff);
        const short8 Al = *(const short8*)(alp + abase[mf] + toff);
#pragma unroll
        for (int nf = 0; nf < 4; ++nf) {
          acc[mf][nf] = mfma16(Ah, Bh[nf], acc[mf][nf]);
          acc[mf][nf] = mfma16(Ah, Bl[nf], acc[mf][nf]);
          acc[mf][nf] = mfma16(Al, Bh[nf], acc[mf][nf]);
        }
      }
    }
    if (pre) {
      short* lb = s_half ? (b ? al0 : al1) : (b ? ah0 : ah1);
#pragma unroll
      for (int k = 0; k < NIT; ++k)
        if (NITEM % 256 == 0 || k * 256 + tid < NITEM)
          *(short4v*)(lb + s_loff[k]) = rv[k];
    }
    __syncthreads();
  }

  float scv[4], shv[4];
#pragma unroll
  for (int nf = 0; nf < 4; ++nf) {
    const int co = n0 + nf * 16 + lrow;
    const float sc = gg[co] * rsqrtf(vg[co] + BN_EPS);
    scv[nf] = sc; shv[nf] = bg[co] - mg[co] * sc;
  }

  if constexpr (!FUSE) {
#pragma unroll
    for (int mf = 0; mf < MF; ++mf)
#pragma unroll
      for (int reg = 0; reg < 4; ++reg) {
        const int pidx = p0 + mf * 16 + (quad << 2) + reg;
        if (pidx < NPIX) {
          const int r = pidx / C, c = pidx % C;
          const int oh = 2 * r + p, ow = 2 * c + q;
          const size_t base =
              ((size_t)(n * H_OUT + oh) * W_OUT + ow) * 256 + n0 + lrow;
#pragma unroll
          for (int nf = 0; nf < 4; ++nf) {
            const float v = fmaxf(0.f, fmaf(acc[mf][nf][reg], scv[nf], shv[nf]));
            short h, l; bf16split(v, h, l);
            oh_[base + nf * 16] = h;
            ol_[base + nf * 16] = l;
          }
        }
      }
  } else {
    constexpr int NSUB = MT / 32;
    const int co_out = (wid << 4) + lrow;       // head channel (waves 0,1)
#pragma unroll                                  // FULL unroll: static acc idx
    for (int s = 0; s < NSUB; ++s) {
      __syncthreads();
#pragma unroll
      for (int mh = 0; mh < 2; ++mh) {
        const int mf = 2 * s + mh;
        const int pl = (mh << 4) + (quad << 2);
#pragma unroll
        for (int reg = 0; reg < 4; ++reg)
#pragma unroll
          for (int nf = 0; nf < 4; ++nf) {
            const float v = fmaxf(0.f, fmaf(acc[mf][nf][reg], scv[nf], shv[nf]));
            short h, l; bf16split(v, h, l);
            const int o = (pl + reg) * YSP + n0 + nf * 16 + lrow;
            ysh_s[o] = h; ysl_s[o] = l;
          }
      }
      __syncthreads();
      if (wid < 2) {
        float4v hacc[2];
        hacc[0] = (float4v){0.f, 0.f, 0.f, 0.f};
        hacc[1] = (float4v){0.f, 0.f, 0.f, 0.f};
#pragma unroll
        for (int ch = 0; ch < 8; ++ch) {
          const size_t bo = (size_t)(ch * 2 + wid) * 512 + lane * 8;
          const short8 Hh = *(const short8*)(wfh + bo);
          const short8 Hl = *(const short8*)(wfl + bo);
#pragma unroll
          for (int mh = 0; mh < 2; ++mh) {
            const int yo = (mh * 16 + lrow) * YSP + (ch << 5) + (quad << 3);
            const short8 Ah = *(const short8*)(ysh_s + yo);
            const short8 Al = *(const short8*)(ysl_s + yo);
            hacc[mh] = mfma16(Ah, Hh, hacc[mh]);
            hacc[mh] = mfma16(Ah, Hl, hacc[mh]);
            hacc[mh] = mfma16(Al, Hh, hacc[mh]);
          }
        }
        if (co_out < 17) {
          const float bias = bfg[co_out];
#pragma unroll
          for (int mh = 0; mh < 2; ++mh)
#pragma unroll
            for (int reg = 0; reg < 4; ++reg) {
              const int pidx = p0 + s * 32 + mh * 16 + (quad << 2) + reg;
              if (pidx < NPIX) {
                const int r = pidx / C, c = pidx % C;
                const int oh = 2 * r + p, ow = 2 * c + q;
                og[((size_t)(n * H_OUT + oh) * W_OUT + ow) * 17 + co_out] =
                    hacc[mh][reg] + bias;
              }
            }
        }
      }
    }
  }
}

// ---------------------------------------------------------------------------
// deconv1: batch folded into M (2240), MT=112 -> 20 tiles; K-split x8 over
// ci; partial accumulation into P0 (ks 0-3) / P1 (ks 4-7); reduction + BN
// in bn1_reduce_split.  EXACT r16 body (best-total-proven 536 us config):
// 256 thr / 4 waves, single-buffer LDS 30.7 KB, lock-step 2-barrier chunk
// schedule (keeps 7.3 MB/XCD working set L2-warm), issue-early loads.
// 1D grid(640): ks = id%8 (== XCD), slot=id/8, tile=slot%20, py=slot/20.
// ---------------------------------------------------------------------------
template <int MT, int KS>
__global__ __launch_bounds__(256, 2) void deconv1_mfma(
    const float* __restrict__ xg,
    const short* __restrict__ wbh, const short* __restrict__ wbl,
    float* __restrict__ P0, float* __restrict__ P1)
{
  constexpr int CIN = 2048, NCH = 64, H_IN = 8, W_IN = 6;
  constexpr int MF = MT / 16;              // 7
  constexpr int NSPAN = 4, CIP = 40;
  constexpr int NCK = CIN / 32 / KS;       // 8 ci-chunks per block
  constexpr int NTILE = 2240 / MT;         // 20
  constexpr int POS = NSPAN * 48;          // 192 staged positions
  constexpr int AN = POS * CIP;            // 7680 shorts per plane
  constexpr int NIT = POS * 16 / 256;      // 12 float2 items per thread

  __shared__ __align__(16) short ah_s[AN];
  __shared__ __align__(16) short al_s[AN];

  const int tid = threadIdx.x;
  const int wid = tid >> 6, lane = tid & 63;
  const int quad = lane >> 4, lrow = lane & 15;
  const int n0 = wid << 6;

  // ---- XCD-aware work decode (r14/r16-proven) ----
  const int id = (int)blockIdx.x;
  const int ks = id & 7;                   // K-split slice == XCD
  const int slot = id >> 3;                // 0..79
  const int tile = slot % NTILE;
  const int py = slot / NTILE;             // parity index 0..3
  const int p = py >> 1, q = py & 1;

  int tapid[4];
#pragma unroll
  for (int t = 0; t < 4; ++t)
    tapid[t] = ((1 - p + 2 * (t >> 1)) << 2) + (1 - q + 2 * (t & 1));

  const int m0 = tile * MT;
  const int n_base = m0 / 35;

  int abase[MF];
#pragma unroll
  for (int mf = 0; mf < MF; ++mf) {
    const int mg_ = m0 + mf * 16 + lrow;   // < 2240 always
    const int nl = mg_ / 35 - n_base;      // <= 3 (m0%35 in {0,7,14,21,28})
    const int pix = mg_ % 35;
    const int r = pix / 5, c = pix % 5;
    abase[mf] = ((nl * H_IN + r) * W_IN + c) * CIP + (quad << 3);
  }

  // ---- staging offsets: item i = k*256+tid; cc2 = tid&15 (const!),
  // pos = k*16 + (tid>>4). ----
  const int tp = tid >> 4, cc2 = tid & 15;
  int goff[NIT];
#pragma unroll
  for (int k = 0; k < NIT; ++k) {
    const int pos = k * 16 + tp;
    const int nl = pos / 48, loc = pos - nl * 48;
    int ng = n_base + nl;
    if (ng > 63) ng = 63;                  // clamp: never consumed
    goff[k] = (ng * 48 + loc) * CIN + cc2 * 2;
  }
  const int loff0 = tp * CIP + cc2 * 2;

  float4v acc[MF][4];
#pragma unroll
  for (int mf = 0; mf < MF; ++mf)
#pragma unroll
    for (int nf = 0; nf < 4; ++nf) acc[mf][nf] = (float4v){0.f, 0.f, 0.f, 0.f};

  const int cibase = ks * (CIN / KS);
  float2 rv[NIT];
  // ---- prologue: load chunk 0 ----
#pragma unroll
  for (int k = 0; k < NIT; ++k)
    rv[k] = *(const float2*)(xg + goff[k] + cibase);

  // ---- main loop: single buffer; sync -> write regs -> sync -> issue next
  // loads -> compute (r16 lock-step; traffic-optimal for 7.3 MB/XCD). ----
#pragma unroll 1
  for (int ck = 0; ck < NCK; ++ck) {
    __syncthreads();                       // prior compute done reading buf
#pragma unroll
    for (int k = 0; k < NIT; ++k) {
      short h0, l0, h1, l1;
      bf16split(rv[k].x, h0, l0); bf16split(rv[k].y, h1, l1);
      const int o = loff0 + k * 16 * CIP;
      *(uint*)(ah_s + o) = pack2(h0, h1);
      *(uint*)(al_s + o) = pack2(l0, l1);
    }
    __syncthreads();                       // buf ready
    if (ck + 1 < NCK) {
      const int ci0 = cibase + (ck + 1) * 32;
#pragma unroll
      for (int k = 0; k < NIT; ++k)
        rv[k] = *(const float2*)(xg + goff[k] + ci0);
    }
    const int ch = ks * NCK + ck;          // global ci-chunk id for weights
#pragma unroll
    for (int t = 0; t < 4; ++t) {
      short8 Bh[4], Bl[4];
#pragma unroll
      for (int nf = 0; nf < 4; ++nf) {
        const size_t fo =
            ((size_t)((tapid[t] * NCH + ch) * 16 + (wid << 2) + nf)) * 512 + lane * 8;
        Bh[nf] = *(const short8*)(wbh + fo);
        Bl[nf] = *(const short8*)(wbl + fo);
      }
      const int toff = ((t >> 1) * W_IN + (t & 1)) * CIP;
#pragma unroll
      for (int mf = 0; mf < MF; ++mf) {
        const short8 Ah = *(const short8*)(ah_s + abase[mf] + toff);
        const short8 Al = *(const short8*)(al_s + abase[mf] + toff);
#pragma unroll
        for (int nf = 0; nf < 4; ++nf) {
          acc[mf][nf] = mfma16(Ah, Bh[nf], acc[mf][nf]);
          acc[mf][nf] = mfma16(Ah, Bl[nf], acc[mf][nf]);
          acc[mf][nf] = mfma16(Al, Bh[nf], acc[mf][nf]);
        }
      }
    }
  }

  // partial accumulation: ks 0-3 -> P0, ks 4-7 -> P1 (4-way contention each)
  float* __restrict__ Pb = (ks & 4) ? P1 : P0;
#pragma unroll
  for (int mf = 0; mf < MF; ++mf)
#pragma unroll
    for (int reg = 0; reg < 4; ++reg) {
      const int mg_ = m0 + mf * 16 + (quad << 2) + reg;
      const int nn = mg_ / 35, pix = mg_ % 35;
      const int r = pix / 5, c = pix % 5;
      const int oh = 2 * r + p, ow = 2 * c + q;
      float* dst = Pb + ((size_t)(nn * 14 + oh) * 10 + ow) * 256 + n0 + lrow;
#pragma unroll
      for (int nf = 0; nf < 4; ++nf)
        atomicAdd(dst + nf * 16, acc[mf][nf][reg]);
    }
}

// P0+P1 -> BN -> ReLU -> split bf16 planes y1h/y1l (co = elem & 255).
__global__ __launch_bounds__(256) void bn1_reduce_split(
    const float* __restrict__ P0, const float* __restrict__ P1,
    short* __restrict__ yh, short* __restrict__ yl,
    const float* __restrict__ gg, const float* __restrict__ bg,
    const float* __restrict__ mg, const float* __restrict__ vg, int nquad)
{
  for (int i = blockIdx.x * 256 + threadIdx.x; i < nquad; i += gridDim.x * 256) {
    const float4v a = *(const float4v*)(P0 + (size_t)i * 4);
    const float4v b = *(const float4v*)(P1 + (size_t)i * 4);
    const int co0 = (i * 4) & 255;
    short4v hv, lv;
#pragma unroll
    for (int j = 0; j < 4; ++j) {
      const int co = co0 + j;
      const float sc = gg[co] * rsqrtf(vg[co] + BN_EPS);
      const float v = fmaxf(0.f, fmaf(a[j] + b[j], sc, bg[co] - mg[co] * sc));
      short h, l; bf16split(v, h, l);
      hv[j] = h; lv[j] = l;
    }
    *(short4v*)(yh + (size_t)i * 4) = hv;
    *(short4v*)(yl + (size_t)i * 4) = lv;
  }
}

// ---------------------------------------------------------------------------
// Heatmap max detection on [64, 50, 34, 17]: one block per (b, k).
// ---------------------------------------------------------------------------
__global__ __launch_bounds__(256) void heatmap_det(const float* __restrict__ hm,
                                                   float* __restrict__ out)
{
  constexpr int H = 50, W = 34, HW = H * W, K = 17;
  const int b = blockIdx.x, k = blockIdx.y;
  const int tid = threadIdx.x;

  float best = -INFINITY;
  int bi = 0;
  for (int pos = tid; pos < HW; pos += 256) {
    const float v = hm[((size_t)b * HW + pos) * K + k];
    if (v > best) { best = v; bi = pos; }
  }
  __shared__ float sv[256];
  __shared__ int si[256];
  sv[tid] = best; si[tid] = bi;
  __syncthreads();
  for (int s = 128; s > 0; s >>= 1) {
    if (tid < s) {
      const float v2 = sv[tid + s]; const int i2 = si[tid + s];
      if (v2 > sv[tid] || (v2 == sv[tid] && i2 < si[tid])) { sv[tid] = v2; si[tid] = i2; }
    }
    __syncthreads();
  }
  if (tid == 0) {
    const float score = sv[0];
    const int idx = si[0];
    float ptx = 0.f, pty = 0.f;
    if (score > 0.f) {
      const int px = idx % W, py = idx / W;
      float dx = 0.f, dy = 0.f;
      if (px > 0 && px < W - 1 && py > 0 && py < H - 1) {
        auto g = [&](int off) {
          int i = idx + off;
          i = i < 0 ? 0 : (i > HW - 1 ? HW - 1 : i);
          return hm[((size_t)b * HW + i) * K + k];
        };
        const float d1 = g(1) - g(-1);
        const float d2 = g(W) - g(-W);
        dx = d1 > 0.f ? 0.25f : (d1 < 0.f ? -0.25f : 0.f);
        dy = d2 > 0.f ? 0.25f : (d2 < 0.f ? -0.25f : 0.f);
      }
      ptx = (float)px + dx;
      pty = (float)py + dy;
    }
    out[((size_t)b * K + k) * 3 + 0] = ptx;
    out[((size_t)b * K + k) * 3 + 1] = pty;
    out[((size_t)b * K + k) * 3 + 2] = score;
  }
}

// ---------------------------------------------------------------------------
extern "C" void kernel_launch(void* const* d_in, const int* in_sizes, int n_in,
                              void* d_out, int out_size, void* d_ws, size_t ws_size,
                              hipStream_t stream)
{
  const float* x  = (const float*)d_in[0];
  const float* w1 = (const float*)d_in[1];
  const float* g1 = (const float*)d_in[2];
  const float* b1 = (const float*)d_in[3];
  const float* m1 = (const float*)d_in[4];
  const float* v1 = (const float*)d_in[5];
  const float* w2 = (const float*)d_in[6];
  const float* g2 = (const float*)d_in[7];
  const float* b2 = (const float*)d_in[8];
  const float* m2 = (const float*)d_in[9];
  const float* v2 = (const float*)d_in[10];
  const float* w3 = (const float*)d_in[11];
  const float* g3 = (const float*)d_in[12];
  const float* b3 = (const float*)d_in[13];
  const float* m3 = (const float*)d_in[14];
  const float* v3 = (const float*)d_in[15];
  const float* wf = (const float*)d_in[16];
  const float* bf = (const float*)d_in[17];

  char* ws = (char*)d_ws;
  // Timeline-aliased layout (max offset 51,904,512 -- same as r16):
  //   region                 live span                 bytes
  //   P0      [0, 9,175,040)           deconv1 -> bn1_reduce
  //   P1      [9,175,040, 18,350,080)  deconv1 -> bn1_reduce
  //   y2h     [0, 15,335,424)          deconv2 -> deconv3   (alias P, dead)
  //   hm      [15,335,424, 22,733,824) deconv3 -> det  (alias y2h-end+y1h)
  //   w1h/w1l [18,350,080, 51,904,512) convert -> deconv1
  //   y1h     [18,350,080, 22,937,600) bn1 -> deconv2  (alias dead w1)
  //   y1l     [22,937,600, 27,525,120) bn1 -> deconv2
  //   y2l     [27,525,120, 42,860,544) deconv2 -> deconv3 (dead w1 tail)
  //   w2h/w2l [42,860,544, 47,054,848) convert(after deconv1) -> deconv2
  //   w3h/w3l [47,054,848, 51,249,152) convert(after deconv1) -> deconv3
  //   wfh/wfl [51,249,152, 51,281,920) convert(after deconv1) -> deconv3
  float* P0  = (float*)(ws + 0);
  float* P1  = (float*)(ws + 9175040);
  short* y2h = (short*)(ws + 0);
  float* hm  = (float*)(ws + 15335424);
  short* w1h = (short*)(ws + 18350080);
  short* w1l = (short*)(ws + 35127296);
  short* y1h = (short*)(ws + 18350080);
  short* y1l = (short*)(ws + 22937600);
  short* y2l = (short*)(ws + 27525120);
  short* w2h = (short*)(ws + 42860544);
  short* w2l = (short*)(ws + 44957696);
  short* w3h = (short*)(ws + 47054848);
  short* w3l = (short*)(ws + 49152000);
  short* wfh = (short*)(ws + 51249152);
  short* wfl = (short*)(ws + 51265536);

  // w1 conversion + partial-buffer zero-init
  convert_w<2048><<<dim3(16, 64, 8), 256, 0, stream>>>(w1, w1h, w1l);
  hipMemsetAsync(P0, 0, 18350080, stream);      // covers P0 and P1

  // deconv1: K-split x8, partials into P0/P1, then reduce+BN+ReLU+split
  deconv1_mfma<112, 8><<<dim3(640), 256, 0, stream>>>(x, w1h, w1l, P0, P1);
  bn1_reduce_split<<<dim3(1024), 256, 0, stream>>>(P0, P1, y1h, y1l,
                                                   g1, b1, m1, v1,
                                                   64 * 14 * 10 * 256 / 4);

  // w2/w3/wf conversion into the now-dead w1 region
  convert_w<256><<<dim3(16, 8, 8), 256, 0, stream>>>(w2, w2h, w2l);
  convert_w<256><<<dim3(16, 8, 8), 256, 0, stream>>>(w3, w3h, w3l);
  convert_wf<<<dim3(16), 256, 0, stream>>>(wf, wfh, wfl);

  // deconv2: NPIX=117, MT=32 -> 4 tiles -> 1024 blocks; split bf16 out
  deconv_mfma<256, 14, 10, 32, false, false><<<dim3(4, 4, 64), 256, 0, stream>>>(
      y1h, y1l, w2h, w2l, g2, b2, m2, v2, nullptr, y2h, y2l,
      nullptr, nullptr, nullptr);

  // deconv3 + fused MFMA head: NPIX=425, MT=96 -> 5 tiles; XCD-pinned 1D
  // grid(1280): xcd=id&7 -> py=xcd>>1 (w3 parity slice 1 MB L2-resident),
  // half=xcd&1; slot=id>>3 -> tile=slot%5, n=half*32+slot/5.
  deconv_mfma<256, 26, 18, 96, true, true><<<dim3(1280), 256, 0, stream>>>(
      y2h, y2l, w3h, w3l, g3, b3, m3, v3, hm, nullptr, nullptr, wfh, wfl, bf);

  // detection
  heatmap_det<<<dim3(64, 17), 256, 0, stream>>>(hm, (float*)d_out);
}